// Round 1
// baseline (444.457 us; speedup 1.0000x reference)
//
#include <hip/hip_runtime.h>
#include <hip/hip_bf16.h>

typedef unsigned short u16;
typedef __bf16 bf16x8 __attribute__((ext_vector_type(8)));
typedef float f32x4 __attribute__((ext_vector_type(4)));

// Problem constants (B=4, S=2048, D=4096, E=8, r=8)
constexpr int Mdim = 8192;   // B*S
constexpr int Ndim = 4096;   // D (output features)
constexpr int Kdim = 4096;   // D (input features)
constexpr int ER   = 64;     // E*r
constexpr float LSCALE = 2.0f;  // alpha/r = 16/8

// round-to-nearest-even fp32 -> bf16 (finite inputs)
__device__ __forceinline__ u16 f2bf(float f) {
    union { float f; unsigned u; } v; v.f = f;
    unsigned r = v.u + 0x7fffu + ((v.u >> 16) & 1u);
    return (u16)(r >> 16);
}

#define GLOAD_LDS16(g, l)                                             \
    __builtin_amdgcn_global_load_lds(                                 \
        (const __attribute__((address_space(1))) void*)(g),           \
        (__attribute__((address_space(3))) void*)(l), 16, 0, 0)

// ---------------------------------------------------------------------------
// Kernel 1: W_eff[o,i] = W[o,i] + SCALE * sum_{er} Bcat[o,er]*Acat[er,i]  (bf16)
// A is [E][r][D] -> Acat[er][i] contiguous. Bm is [E][D][r] -> gather.
// Block: 256 threads, tile 64(o) x 128(i). Grid: (Ndim/64) x (Kdim/128) = 64x32.
// ---------------------------------------------------------------------------
__global__ __launch_bounds__(256) void weff_kernel(
    const float* __restrict__ W, const float* __restrict__ A,
    const float* __restrict__ Bm, u16* __restrict__ Wb)
{
    __shared__ __align__(16) float sAc[ER][128];  // 32 KB
    __shared__ __align__(16) float sBc[64][ER];   // 16 KB

    const int t  = threadIdx.x;
    const int i0 = blockIdx.x * 128;
    const int o0 = blockIdx.y * 64;

    // stage Acat tile [64 er][128 i]
#pragma unroll
    for (int p = 0; p < 8; ++p) {
        int lin = p * 1024 + t * 4;
        int er = lin >> 7, ci = lin & 127;
        *(float4*)&sAc[er][ci] = *(const float4*)(A + (size_t)er * Kdim + i0 + ci);
    }
    // stage Bcat tile [64 o][64 er];  Bm[e][o][r] = Bm[(e*D + o)*8 + r]
    {
        int ol = t >> 2;
        int c  = (t & 3) * 16;
#pragma unroll
        for (int q = 0; q < 2; ++q) {
            int er = c + q * 8;
            int e  = er >> 3;
            const float* src = Bm + ((size_t)e * Ndim + (o0 + ol)) * 8;
            *(float4*)&sBc[ol][er]     = *(const float4*)(src);
            *(float4*)&sBc[ol][er + 4] = *(const float4*)(src + 4);
        }
    }
    __syncthreads();

    const int tx = t & 31;   // i_local = tx*4
    const int ty = t >> 5;   // o_local = q*8 + ty
    float acc[8][4] = {};
#pragma unroll 4
    for (int er = 0; er < ER; ++er) {
        float4 a = *(const float4*)&sAc[er][tx * 4];
#pragma unroll
        for (int q = 0; q < 8; ++q) {
            float bv = sBc[q * 8 + ty][er];
            acc[q][0] += bv * a.x;
            acc[q][1] += bv * a.y;
            acc[q][2] += bv * a.z;
            acc[q][3] += bv * a.w;
        }
    }
#pragma unroll
    for (int q = 0; q < 8; ++q) {
        int o = o0 + q * 8 + ty;
        const float4 w = *(const float4*)(W + (size_t)o * Kdim + i0 + tx * 4);
        ushort4 st;
        st.x = f2bf(w.x + LSCALE * acc[q][0]);
        st.y = f2bf(w.y + LSCALE * acc[q][1]);
        st.z = f2bf(w.z + LSCALE * acc[q][2]);
        st.w = f2bf(w.w + LSCALE * acc[q][3]);
        *(ushort4*)(Wb + (size_t)o * Kdim + i0 + tx * 4) = st;
    }
}

// ---------------------------------------------------------------------------
// Kernel 2: x fp32 -> bf16, 8 elements/thread
// ---------------------------------------------------------------------------
__global__ __launch_bounds__(256) void cvt_x_kernel(
    const float* __restrict__ x, u16* __restrict__ xb)
{
    size_t i = (size_t)blockIdx.x * blockDim.x + threadIdx.x;
    const float4 v0 = *(const float4*)(x + i * 8);
    const float4 v1 = *(const float4*)(x + i * 8 + 4);
    uint4 o;
    o.x = (unsigned)f2bf(v0.x) | ((unsigned)f2bf(v0.y) << 16);
    o.y = (unsigned)f2bf(v0.z) | ((unsigned)f2bf(v0.w) << 16);
    o.z = (unsigned)f2bf(v1.x) | ((unsigned)f2bf(v1.y) << 16);
    o.w = (unsigned)f2bf(v1.z) | ((unsigned)f2bf(v1.w) << 16);
    *(uint4*)(xb + i * 8) = o;
}

// ---------------------------------------------------------------------------
// Kernel 3: C[m,n] = sum_k Xb[m,k]*Wb[n,k] + bias[n]   (m97 structure)
// 128x128 tile, BK=64, 4 waves (2x2), each wave 64x64 = 4x4 frags of 16x16x32.
// ---------------------------------------------------------------------------
constexpr int BM = 128, BN = 128, BK = 64;

__global__ __launch_bounds__(256) void gemm_bias_kernel(
    const u16* __restrict__ Xb, const u16* __restrict__ Wb,
    const float* __restrict__ bias, float* __restrict__ C)
{
    __shared__ __align__(16) u16 sA[BM * BK];  // 16 KB
    __shared__ __align__(16) u16 sB[BN * BK];  // 16 KB

    const int t    = threadIdx.x;
    const int lane = t & 63;
    const int wv   = t >> 6;
    const int wr   = wv >> 1, wc = wv & 1;

    const int bm = blockIdx.y * BM;
    const int bn = blockIdx.x * BN;

    const int srow = t >> 3;        // 0..31 (row within 32-row staging group)
    const int scol = (t & 7) * 8;   // bf16 element col (16B chunks)

    f32x4 acc[4][4];
#pragma unroll
    for (int i = 0; i < 4; ++i)
#pragma unroll
        for (int j = 0; j < 4; ++j)
            acc[i][j] = f32x4{0.f, 0.f, 0.f, 0.f};

    for (int k0 = 0; k0 < Kdim; k0 += BK) {
        // stage A tile (128x64 bf16) and B tile via global_load_lds width 16
#pragma unroll
        for (int it = 0; it < 4; ++it) {
            int row = it * 32 + srow;
            GLOAD_LDS16(Xb + (size_t)(bm + row) * Kdim + k0 + scol,
                        sA + row * BK + scol);
        }
#pragma unroll
        for (int it = 0; it < 4; ++it) {
            int row = it * 32 + srow;
            GLOAD_LDS16(Wb + (size_t)(bn + row) * Kdim + k0 + scol,
                        sB + row * BK + scol);
        }
        __syncthreads();

#pragma unroll
        for (int kk = 0; kk < 2; ++kk) {
            bf16x8 af[4], bfr[4];
#pragma unroll
            for (int mi = 0; mi < 4; ++mi) {
                int row = wr * 64 + mi * 16 + (lane & 15);
                af[mi] = *(const bf16x8*)(sA + row * BK + kk * 32 + (lane >> 4) * 8);
            }
#pragma unroll
            for (int ni = 0; ni < 4; ++ni) {
                int row = wc * 64 + ni * 16 + (lane & 15);
                bfr[ni] = *(const bf16x8*)(sB + row * BK + kk * 32 + (lane >> 4) * 8);
            }
#pragma unroll
            for (int mi = 0; mi < 4; ++mi)
#pragma unroll
                for (int ni = 0; ni < 4; ++ni)
                    acc[mi][ni] = __builtin_amdgcn_mfma_f32_16x16x32_bf16(
                        af[mi], bfr[ni], acc[mi][ni], 0, 0, 0);
        }
        __syncthreads();
    }

    // epilogue: C/D layout col = lane&15, row = (lane>>4)*4 + j
#pragma unroll
    for (int ni = 0; ni < 4; ++ni) {
        int col = bn + wc * 64 + ni * 16 + (lane & 15);
        float bv = bias[col];
#pragma unroll
        for (int mi = 0; mi < 4; ++mi) {
            int rbase = bm + wr * 64 + mi * 16 + (lane >> 4) * 4;
#pragma unroll
            for (int j = 0; j < 4; ++j)
                C[(size_t)(rbase + j) * Ndim + col] = acc[mi][ni][j] + bv;
        }
    }
}

// ---------------------------------------------------------------------------
// Fallback (only if ws too small): slow but correct fp32 row-per-block kernel
// ---------------------------------------------------------------------------
__global__ __launch_bounds__(256) void naive_row_kernel(
    const float* __restrict__ x, const float* __restrict__ W,
    const float* __restrict__ bias, const float* __restrict__ A,
    const float* __restrict__ Bm, float* __restrict__ out)
{
    __shared__ float sx[Kdim];
    __shared__ float st[ER];
    const int m = blockIdx.x;
    const float* xr = x + (size_t)m * Kdim;
    for (int i = threadIdx.x; i < Kdim; i += 256) sx[i] = xr[i];
    __syncthreads();
    if (threadIdx.x < ER) {
        const float* ar = A + (size_t)threadIdx.x * Kdim;
        float s = 0.f;
        for (int i = 0; i < Kdim; ++i) s += sx[i] * ar[i];
        st[threadIdx.x] = s;
    }
    __syncthreads();
    for (int o = threadIdx.x; o < Ndim; o += 256) {
        const float* wr = W + (size_t)o * Kdim;
        float s = bias[o];
        for (int i = 0; i < Kdim; ++i) s += sx[i] * wr[i];
        float l = 0.f;
        for (int e = 0; e < 8; ++e) {
            const float* bp = Bm + ((size_t)e * Ndim + o) * 8;
            for (int r = 0; r < 8; ++r) l += st[e * 8 + r] * bp[r];
        }
        out[(size_t)m * Ndim + o] = s + LSCALE * l;
    }
}

extern "C" void kernel_launch(void* const* d_in, const int* in_sizes, int n_in,
                              void* d_out, int out_size, void* d_ws, size_t ws_size,
                              hipStream_t stream)
{
    const float* x  = (const float*)d_in[0];
    const float* W  = (const float*)d_in[1];
    const float* b  = (const float*)d_in[2];
    const float* A  = (const float*)d_in[3];
    const float* Bm = (const float*)d_in[4];
    float* out = (float*)d_out;

    const size_t xb_bytes = (size_t)Mdim * Kdim * 2;   // 64 MB
    const size_t wb_bytes = (size_t)Ndim * Kdim * 2;   // 32 MB

    if (ws_size >= xb_bytes + wb_bytes) {
        u16* Xb = (u16*)d_ws;
        u16* Wb = (u16*)((char*)d_ws + xb_bytes);
        cvt_x_kernel<<<(Mdim * (size_t)Kdim) / 8 / 256, 256, 0, stream>>>(x, Xb);
        weff_kernel<<<dim3(Kdim / 128, Ndim / 64), 256, 0, stream>>>(W, A, Bm, Wb);
        gemm_bias_kernel<<<dim3(Ndim / BN, Mdim / BM), 256, 0, stream>>>(Xb, Wb, b, out);
    } else {
        naive_row_kernel<<<Mdim, 256, 0, stream>>>(x, W, b, A, Bm, out);
    }
}

// Round 3
// 327.289 us; speedup vs baseline: 1.3580x; 1.3580x over previous
//
#include <hip/hip_runtime.h>
#include <hip/hip_bf16.h>

typedef unsigned short u16;
typedef __bf16 bf16x8 __attribute__((ext_vector_type(8)));
typedef float f32x4 __attribute__((ext_vector_type(4)));

// Problem constants (B=4, S=2048, D=4096, E=8, r=8)
constexpr int Mdim = 8192;   // B*S
constexpr int Ndim = 4096;   // D (output features)
constexpr int Kdim = 4096;   // D (input features)
constexpr int ER   = 64;     // E*r
constexpr float LSCALE = 2.0f;  // alpha/r = 16/8

// round-to-nearest-even fp32 -> bf16 (finite inputs)
__device__ __forceinline__ u16 f2bf(float f) {
    union { float f; unsigned u; } v; v.f = f;
    unsigned r = v.u + 0x7fffu + ((v.u >> 16) & 1u);
    return (u16)(r >> 16);
}

#define GLOAD_LDS16(g, l)                                             \
    __builtin_amdgcn_global_load_lds(                                 \
        (const __attribute__((address_space(1))) void*)(g),           \
        (__attribute__((address_space(3))) void*)(l), 16, 0, 0)

// ---------------------------------------------------------------------------
// Kernel 1: W_eff[o,i] = W[o,i] + SCALE * sum_{er} Bcat[o,er]*Acat[er,i] (bf16)
// ---------------------------------------------------------------------------
__global__ __launch_bounds__(256) void weff_kernel(
    const float* __restrict__ W, const float* __restrict__ A,
    const float* __restrict__ Bm, u16* __restrict__ Wb)
{
    __shared__ __align__(16) float sAc[ER][128];
    __shared__ __align__(16) float sBc[64][ER];

    const int t  = threadIdx.x;
    const int i0 = blockIdx.x * 128;
    const int o0 = blockIdx.y * 64;

#pragma unroll
    for (int p = 0; p < 8; ++p) {
        int lin = p * 1024 + t * 4;
        int er = lin >> 7, ci = lin & 127;
        *(float4*)&sAc[er][ci] = *(const float4*)(A + (size_t)er * Kdim + i0 + ci);
    }
    {
        int ol = t >> 2;
        int c  = (t & 3) * 16;
#pragma unroll
        for (int q = 0; q < 2; ++q) {
            int er = c + q * 8;
            int e  = er >> 3;
            const float* src = Bm + ((size_t)e * Ndim + (o0 + ol)) * 8;
            *(float4*)&sBc[ol][er]     = *(const float4*)(src);
            *(float4*)&sBc[ol][er + 4] = *(const float4*)(src + 4);
        }
    }
    __syncthreads();

    const int tx = t & 31;
    const int ty = t >> 5;
    float acc[8][4] = {};
#pragma unroll 4
    for (int er = 0; er < ER; ++er) {
        float4 a = *(const float4*)&sAc[er][tx * 4];
#pragma unroll
        for (int q = 0; q < 8; ++q) {
            float bv = sBc[q * 8 + ty][er];
            acc[q][0] += bv * a.x;
            acc[q][1] += bv * a.y;
            acc[q][2] += bv * a.z;
            acc[q][3] += bv * a.w;
        }
    }
#pragma unroll
    for (int q = 0; q < 8; ++q) {
        int o = o0 + q * 8 + ty;
        const float4 w = *(const float4*)(W + (size_t)o * Kdim + i0 + tx * 4);
        ushort4 st;
        st.x = f2bf(w.x + LSCALE * acc[q][0]);
        st.y = f2bf(w.y + LSCALE * acc[q][1]);
        st.z = f2bf(w.z + LSCALE * acc[q][2]);
        st.w = f2bf(w.w + LSCALE * acc[q][3]);
        *(ushort4*)(Wb + (size_t)o * Kdim + i0 + tx * 4) = st;
    }
}

// ---------------------------------------------------------------------------
// Kernel 2: x fp32 -> bf16, 8 elements/thread
// ---------------------------------------------------------------------------
__global__ __launch_bounds__(256) void cvt_x_kernel(
    const float* __restrict__ x, u16* __restrict__ xb)
{
    size_t i = (size_t)blockIdx.x * blockDim.x + threadIdx.x;
    const float4 v0 = *(const float4*)(x + i * 8);
    const float4 v1 = *(const float4*)(x + i * 8 + 4);
    uint4 o;
    o.x = (unsigned)f2bf(v0.x) | ((unsigned)f2bf(v0.y) << 16);
    o.y = (unsigned)f2bf(v0.z) | ((unsigned)f2bf(v0.w) << 16);
    o.z = (unsigned)f2bf(v1.x) | ((unsigned)f2bf(v1.y) << 16);
    o.w = (unsigned)f2bf(v1.z) | ((unsigned)f2bf(v1.w) << 16);
    *(uint4*)(xb + i * 8) = o;
}

// ---------------------------------------------------------------------------
// Kernel 3: 256x256 tile GEMM, counted-vmcnt pipeline, swizzled LDS.
// C[m,n] = sum_k Xb[m,k]*Wb[n,k] + bias[n]
// 512 threads = 8 waves (2 M x 4 N); per-wave 128x64 out = acc[8][4] f32x4.
// LDS 128 KiB: A/B tiles (256x64 bf16 = 32 KB each) double-buffered.
// ---------------------------------------------------------------------------
constexpr int BM = 256, BN = 256, BK = 64;
constexpr int NT = Kdim / BK;  // 64

__global__ __launch_bounds__(512, 2) void gemm_bias_kernel(
    const u16* __restrict__ Xb, const u16* __restrict__ Wb,
    const float* __restrict__ bias, float* __restrict__ C)
{
    __shared__ __align__(16) u16 lds[65536];   // 128 KiB

    const int t    = threadIdx.x;
    const int lane = t & 63;
    const int wv   = t >> 6;
    const int wr   = wv >> 2;   // 0..1
    const int wc   = wv & 3;    // 0..3

    // XCD-aware swizzle: 512 blocks = 8 XCDs x 64; each XCD owns a 16x4 region
    const int wg  = blockIdx.x;
    const int xcd = wg & 7, lid = wg >> 3;
    const int mt  = (xcd & 1) * 16 + (lid >> 2);   // 0..31
    const int ntl = (xcd >> 1) * 4 + (lid & 3);    // 0..15
    const int bm  = mt * BM;
    const int bn  = ntl * BN;

    u16* sA0 = lds;          u16* sA1 = lds + 16384;
    u16* sB0 = lds + 32768;  u16* sB1 = lds + 49152;

    // --- staging setup: 4 A-loads + 4 B-loads per thread per tile ---
    // LDS is written LINEARLY by global_load_lds; the SOURCE address is
    // pre-swizzled with the involution (chunk bits 1,2 ^= row bits 2,3)
    // so that swizzled ds_reads below see the right data (rule 21).
    const u16* aSrc[4]; const u16* bSrc[4]; int dOff[4];
#pragma unroll
    for (int i = 0; i < 4; ++i) {
        int c   = i * 512 + t;                                  // 16B chunk id
        int cs  = c ^ (((c >> 5) & 1) << 1) ^ (((c >> 6) & 1) << 2);
        int row = c >> 3;                                       // 0..255
        int col = (cs & 7) * 8;                                 // bf16 col
        aSrc[i] = Xb + (size_t)(bm + row) * Kdim + col;
        bSrc[i] = Wb + (size_t)(bn + row) * Kdim + col;
        dOff[i] = i * 4096 + t * 8;                             // u16 index
    }

    // --- fragment ds_read addressing (swizzled) ---
    const int rl  = (lane & 15) * 64;                            // row*64 low
    const int sx  = (((lane >> 2) & 1) << 4) | (((lane >> 3) & 1) << 5);
    const int cp0 = (((lane >> 4) * 8)) ^ sx;                    // kk=0
    const int cp1 = (32 + (lane >> 4) * 8) ^ sx;                 // kk=1
    const int aBase = wr * 8192 + rl;   // + (mh*4+mi)*1024 + cp{kk}
    const int bBase = wc * 4096 + rl;   // + ni*1024 + cp{kk}

    f32x4 acc[8][4];
#pragma unroll
    for (int i = 0; i < 8; ++i)
#pragma unroll
        for (int j = 0; j < 4; ++j)
            acc[i][j] = f32x4{0.f, 0.f, 0.f, 0.f};

    bf16x8 af[4][2];    // current A m-half fragments
    bf16x8 bfr[4][2];   // all four B n-fragments

#define LOADA(SRC, MH)                                                        \
    _Pragma("unroll")                                                         \
    for (int mi = 0; mi < 4; ++mi) {                                          \
        af[mi][0] = *(const bf16x8*)&SRC[aBase + ((MH)*4 + mi) * 1024 + cp0]; \
        af[mi][1] = *(const bf16x8*)&SRC[aBase + ((MH)*4 + mi) * 1024 + cp1]; \
    }

#define LOADB(SRC, NH)                                                        \
    _Pragma("unroll")                                                         \
    for (int nl = 0; nl < 2; ++nl) {                                          \
        bfr[(NH)*2 + nl][0] = *(const bf16x8*)&SRC[bBase + ((NH)*2 + nl) * 1024 + cp0]; \
        bfr[(NH)*2 + nl][1] = *(const bf16x8*)&SRC[bBase + ((NH)*2 + nl) * 1024 + cp1]; \
    }

#define MQ(MH, NH)                                                            \
    __builtin_amdgcn_s_setprio(1);                                            \
    _Pragma("unroll")                                                         \
    for (int mi = 0; mi < 4; ++mi)                                            \
        _Pragma("unroll")                                                     \
        for (int nl = 0; nl < 2; ++nl) {                                      \
            acc[(MH)*4 + mi][(NH)*2 + nl] =                                   \
                __builtin_amdgcn_mfma_f32_16x16x32_bf16(                      \
                    af[mi][0], bfr[(NH)*2 + nl][0],                           \
                    acc[(MH)*4 + mi][(NH)*2 + nl], 0, 0, 0);                  \
            acc[(MH)*4 + mi][(NH)*2 + nl] =                                   \
                __builtin_amdgcn_mfma_f32_16x16x32_bf16(                      \
                    af[mi][1], bfr[(NH)*2 + nl][1],                           \
                    acc[(MH)*4 + mi][(NH)*2 + nl], 0, 0, 0);                  \
        }                                                                     \
    __builtin_amdgcn_s_setprio(0);

    // ITER(T): [issue tile T+1 into NX buffers]; vmcnt(8) -> tile T landed
    // (loads for T+1 stay in flight across the whole compute); barrier;
    // compute 4 quadrants from CUR buffers; lgkmcnt(0); barrier.
#define ITER(CURA, CURB, NXA, NXB, DOISS, VMS)                                \
    {                                                                         \
        if (DOISS) {                                                          \
            _Pragma("unroll")                                                 \
            for (int i = 0; i < 4; ++i)                                       \
                GLOAD_LDS16(aSrc[i] + koff, (NXA) + dOff[i]);                 \
            _Pragma("unroll")                                                 \
            for (int i = 0; i < 4; ++i)                                       \
                GLOAD_LDS16(bSrc[i] + koff, (NXB) + dOff[i]);                 \
            koff += 64;                                                       \
        }                                                                     \
        asm volatile("s_waitcnt vmcnt(" VMS ")" ::: "memory");                \
        __builtin_amdgcn_s_barrier();                                         \
        asm volatile("" ::: "memory");                                        \
        LOADA(CURA, 0); LOADB(CURB, 0); MQ(0, 0);                             \
        LOADB(CURB, 1); MQ(0, 1);                                             \
        LOADA(CURA, 1); MQ(1, 1);                                             \
        MQ(1, 0);                                                             \
        asm volatile("s_waitcnt lgkmcnt(0)" ::: "memory");                    \
        __builtin_amdgcn_s_barrier();                                         \
        asm volatile("" ::: "memory");                                        \
    }

    // prologue: issue tile 0 into buf0
#pragma unroll
    for (int i = 0; i < 4; ++i) GLOAD_LDS16(aSrc[i], sA0 + dOff[i]);
#pragma unroll
    for (int i = 0; i < 4; ++i) GLOAD_LDS16(bSrc[i], sB0 + dOff[i]);

    int koff = 64;   // k element-offset of the next tile to issue (tile 1)

#pragma unroll 1
    for (int t2 = 0; t2 < NT - 2; t2 += 2) {
        ITER(sA0, sB0, sA1, sB1, 1, "8");
        ITER(sA1, sB1, sA0, sB0, 1, "8");
    }
    ITER(sA0, sB0, sA1, sB1, 1, "8");   // tile 62, issues tile 63
    ITER(sA1, sB1, sA0, sB0, 0, "0");   // tile 63, drain

#undef ITER
#undef MQ
#undef LOADB
#undef LOADA

    // epilogue: bias add + store (C/D layout: col=lane&15, row=(lane>>4)*4+j)
#pragma unroll
    for (int ni = 0; ni < 4; ++ni) {
        const int col = bn + wc * 64 + ni * 16 + (lane & 15);
        const float bv = bias[col];
#pragma unroll
        for (int mi = 0; mi < 8; ++mi) {
            const int rbase = bm + wr * 128 + mi * 16 + (lane >> 4) * 4;
#pragma unroll
            for (int j = 0; j < 4; ++j)
                C[(size_t)(rbase + j) * Ndim + col] = acc[mi][ni][j] + bv;
        }
    }
}

// ---------------------------------------------------------------------------
// Fallback (only if ws too small): slow but correct fp32 row-per-block kernel
// ---------------------------------------------------------------------------
__global__ __launch_bounds__(256) void naive_row_kernel(
    const float* __restrict__ x, const float* __restrict__ W,
    const float* __restrict__ bias, const float* __restrict__ A,
    const float* __restrict__ Bm, float* __restrict__ out)
{
    __shared__ float sx[Kdim];
    __shared__ float st[ER];
    const int m = blockIdx.x;
    const float* xr = x + (size_t)m * Kdim;
    for (int i = threadIdx.x; i < Kdim; i += 256) sx[i] = xr[i];
    __syncthreads();
    if (threadIdx.x < ER) {
        const float* ar = A + (size_t)threadIdx.x * Kdim;
        float s = 0.f;
        for (int i = 0; i < Kdim; ++i) s += sx[i] * ar[i];
        st[threadIdx.x] = s;
    }
    __syncthreads();
    for (int o = threadIdx.x; o < Ndim; o += 256) {
        const float* wr = W + (size_t)o * Kdim;
        float s = bias[o];
        for (int i = 0; i < Kdim; ++i) s += sx[i] * wr[i];
        float l = 0.f;
        for (int e = 0; e < 8; ++e) {
            const float* bp = Bm + ((size_t)e * Ndim + o) * 8;
            for (int r = 0; r < 8; ++r) l += st[e * 8 + r] * bp[r];
        }
        out[(size_t)m * Ndim + o] = s + LSCALE * l;
    }
}

extern "C" void kernel_launch(void* const* d_in, const int* in_sizes, int n_in,
                              void* d_out, int out_size, void* d_ws, size_t ws_size,
                              hipStream_t stream)
{
    const float* x  = (const float*)d_in[0];
    const float* W  = (const float*)d_in[1];
    const float* b  = (const float*)d_in[2];
    const float* A  = (const float*)d_in[3];
    const float* Bm = (const float*)d_in[4];
    float* out = (float*)d_out;

    const size_t xb_bytes = (size_t)Mdim * Kdim * 2;   // 64 MB
    const size_t wb_bytes = (size_t)Ndim * Kdim * 2;   // 32 MB

    if (ws_size >= xb_bytes + wb_bytes) {
        u16* Xb = (u16*)d_ws;
        u16* Wb = (u16*)((char*)d_ws + xb_bytes);
        cvt_x_kernel<<<(Mdim * (size_t)Kdim) / 8 / 256, 256, 0, stream>>>(x, Xb);
        weff_kernel<<<dim3(Kdim / 128, Ndim / 64), 256, 0, stream>>>(W, A, Bm, Wb);
        gemm_bias_kernel<<<dim3((Mdim / BM) * (Ndim / BN)), 512, 0, stream>>>(Xb, Wb, b, out);
    } else {
        naive_row_kernel<<<Mdim, 256, 0, stream>>>(x, W, b, A, Bm, out);
    }
}

// Round 4
// 312.107 us; speedup vs baseline: 1.4241x; 1.0486x over previous
//
#include <hip/hip_runtime.h>
#include <hip/hip_bf16.h>

typedef unsigned short u16;
typedef __bf16 bf16x8 __attribute__((ext_vector_type(8)));
typedef float f32x4 __attribute__((ext_vector_type(4)));

// Problem constants (B=4, S=2048, D=4096, E=8, r=8)
constexpr int Mdim = 8192;   // B*S
constexpr int Ndim = 4096;   // D (output features)
constexpr int Kdim = 4096;   // D (input features)
constexpr int ER   = 64;     // E*r
constexpr float LSCALE = 2.0f;  // alpha/r = 16/8

// round-to-nearest-even fp32 -> bf16 (finite inputs)
__device__ __forceinline__ u16 f2bf(float f) {
    union { float f; unsigned u; } v; v.f = f;
    unsigned r = v.u + 0x7fffu + ((v.u >> 16) & 1u);
    return (u16)(r >> 16);
}

#define GLOAD_LDS16(g, l)                                             \
    __builtin_amdgcn_global_load_lds(                                 \
        (const __attribute__((address_space(1))) void*)(g),           \
        (__attribute__((address_space(3))) void*)(l), 16, 0, 0)

// ---------------------------------------------------------------------------
// Kernel 1: W_eff[o,i] = W[o,i] + SCALE * sum_{er} Bcat[o,er]*Acat[er,i] (bf16)
// ---------------------------------------------------------------------------
__global__ __launch_bounds__(256) void weff_kernel(
    const float* __restrict__ W, const float* __restrict__ A,
    const float* __restrict__ Bm, u16* __restrict__ Wb)
{
    __shared__ __align__(16) float sAc[ER][128];
    __shared__ __align__(16) float sBc[64][ER];

    const int t  = threadIdx.x;
    const int i0 = blockIdx.x * 128;
    const int o0 = blockIdx.y * 64;

#pragma unroll
    for (int p = 0; p < 8; ++p) {
        int lin = p * 1024 + t * 4;
        int er = lin >> 7, ci = lin & 127;
        *(float4*)&sAc[er][ci] = *(const float4*)(A + (size_t)er * Kdim + i0 + ci);
    }
    {
        int ol = t >> 2;
        int c  = (t & 3) * 16;
#pragma unroll
        for (int q = 0; q < 2; ++q) {
            int er = c + q * 8;
            int e  = er >> 3;
            const float* src = Bm + ((size_t)e * Ndim + (o0 + ol)) * 8;
            *(float4*)&sBc[ol][er]     = *(const float4*)(src);
            *(float4*)&sBc[ol][er + 4] = *(const float4*)(src + 4);
        }
    }
    __syncthreads();

    const int tx = t & 31;
    const int ty = t >> 5;
    float acc[8][4] = {};
#pragma unroll 4
    for (int er = 0; er < ER; ++er) {
        float4 a = *(const float4*)&sAc[er][tx * 4];
#pragma unroll
        for (int q = 0; q < 8; ++q) {
            float bv = sBc[q * 8 + ty][er];
            acc[q][0] += bv * a.x;
            acc[q][1] += bv * a.y;
            acc[q][2] += bv * a.z;
            acc[q][3] += bv * a.w;
        }
    }
#pragma unroll
    for (int q = 0; q < 8; ++q) {
        int o = o0 + q * 8 + ty;
        const float4 w = *(const float4*)(W + (size_t)o * Kdim + i0 + tx * 4);
        ushort4 st;
        st.x = f2bf(w.x + LSCALE * acc[q][0]);
        st.y = f2bf(w.y + LSCALE * acc[q][1]);
        st.z = f2bf(w.z + LSCALE * acc[q][2]);
        st.w = f2bf(w.w + LSCALE * acc[q][3]);
        *(ushort4*)(Wb + (size_t)o * Kdim + i0 + tx * 4) = st;
    }
}

// ---------------------------------------------------------------------------
// Kernel 2: x fp32 -> bf16, 8 elements/thread
// ---------------------------------------------------------------------------
__global__ __launch_bounds__(256) void cvt_x_kernel(
    const float* __restrict__ x, u16* __restrict__ xb)
{
    size_t i = (size_t)blockIdx.x * blockDim.x + threadIdx.x;
    const float4 v0 = *(const float4*)(x + i * 8);
    const float4 v1 = *(const float4*)(x + i * 8 + 4);
    uint4 o;
    o.x = (unsigned)f2bf(v0.x) | ((unsigned)f2bf(v0.y) << 16);
    o.y = (unsigned)f2bf(v0.z) | ((unsigned)f2bf(v0.w) << 16);
    o.z = (unsigned)f2bf(v1.x) | ((unsigned)f2bf(v1.y) << 16);
    o.w = (unsigned)f2bf(v1.z) | ((unsigned)f2bf(v1.w) << 16);
    *(uint4*)(xb + i * 8) = o;
}

// ---------------------------------------------------------------------------
// Kernel 3: 256x256x64 GEMM, 4-phase K-loop, counted vmcnt, full XOR swizzle.
// C[m,n] = sum_k Xb[m,k]*Wb[n,k] + bias[n]
// 512 threads = 8 waves (2 M x 4 N); per-wave 128x64 out = acc[8][4] f32x4.
// LDS 128 KiB: per buf {A[256][64], B[256][64]} bf16, double-buffered.
// Swizzle: LDS chunk ch holds global chunk ch^(row&7) (16B chunks, involution,
// applied on the pre-swizzled global source; ds_reads XOR the same key).
// ---------------------------------------------------------------------------
constexpr int BM = 256, BN = 256, BK = 64;
constexpr int NT = Kdim / BK;  // 64

__global__ __launch_bounds__(512, 2) void gemm_bias_kernel(
    const u16* __restrict__ Xb, const u16* __restrict__ Wb,
    const float* __restrict__ bias, float* __restrict__ C)
{
    __shared__ __align__(16) u16 lds[65536];   // 128 KiB

    const int t    = threadIdx.x;
    const int lane = t & 63;
    const int wv   = t >> 6;
    const int wr   = wv >> 2;   // 0..1
    const int wc   = wv & 3;    // 0..3

    // XCD-aware swizzle: 512 blocks = 8 XCDs x 64; each XCD owns a 16x4 region
    const int wg  = blockIdx.x;
    const int xcd = wg & 7, lid = wg >> 3;
    const int mt  = (xcd & 1) * 16 + (lid >> 2);   // 0..31
    const int ntl = (xcd >> 1) * 4 + (lid & 3);    // 0..15
    const int bm  = mt * BM;
    const int bn  = ntl * BN;

    u16* b0 = lds;            // buf0: A at [0,16384), B at [16384,32768)
    u16* b1 = lds + 32768;    // buf1

    // --- staging: 8 x global_load_lds(16B) per thread per K-tile ---
    // load i: i<4 -> A chunk c=i*512+t ; i>=4 -> B chunk c=(i-4)*512+t
    // LDS dest linear (c*8 u16); global source col chunk pre-swizzled:
    // scol = ((c ^ (c>>3)) & 7) * 8  (chunk ^ (row&7), involution)
    const u16* gSrc[8]; int dOff[8];
#pragma unroll
    for (int i = 0; i < 8; ++i) {
        const int sub = i & 3;
        const int isB = i >> 2;
        const int c   = sub * 512 + t;                    // 0..2047
        const int row = c >> 3;                           // 0..255
        const int scl = ((c ^ row) & 7) * 8;              // swizzled col (u16)
        gSrc[i] = (isB ? Wb + (size_t)(bn + row) * Kdim
                       : Xb + (size_t)(bm + row) * Kdim) + scl;
        dOff[i] = isB * 16384 + c * 8;
    }

    // --- fragment ds_read addressing (swizzled) ---
    const int fr  = lane & 15;                               // row-in-16
    const int cp0 = (((lane >> 4)    ) ^ (lane & 7)) * 8;    // kk=0 chunk col
    const int cp1 = (((lane >> 4) + 4) ^ (lane & 7)) * 8;    // kk=1 chunk col

    f32x4 acc[8][4];
#pragma unroll
    for (int i = 0; i < 8; ++i)
#pragma unroll
        for (int j = 0; j < 4; ++j)
            acc[i][j] = f32x4{0.f, 0.f, 0.f, 0.f};

    bf16x8 af[4][2];    // current A m-half fragments (one mh at a time)
    bf16x8 bfr[4][2];   // ALL B n-fragments (held across the K-tile)

#define DS_AF(BUF, MH)                                                        \
    _Pragma("unroll")                                                         \
    for (int mi = 0; mi < 4; ++mi) {                                          \
        const int rb = (wr * 128 + (MH) * 64 + mi * 16 + fr) * 64;            \
        af[mi][0] = *(const bf16x8*)&(BUF)[rb + cp0];                         \
        af[mi][1] = *(const bf16x8*)&(BUF)[rb + cp1];                         \
    }

#define DS_BF(BUF, NH)                                                        \
    _Pragma("unroll")                                                         \
    for (int nl = 0; nl < 2; ++nl) {                                          \
        const int ni = (NH) * 2 + nl;                                         \
        const int rb = 16384 + (wc * 64 + ni * 16 + fr) * 64;                 \
        bfr[ni][0] = *(const bf16x8*)&(BUF)[rb + cp0];                        \
        bfr[ni][1] = *(const bf16x8*)&(BUF)[rb + cp1];                        \
    }

#define MQ(MH, NH)                                                            \
    __builtin_amdgcn_s_setprio(1);                                            \
    _Pragma("unroll")                                                         \
    for (int mi = 0; mi < 4; ++mi)                                            \
        _Pragma("unroll")                                                     \
        for (int nl = 0; nl < 2; ++nl) {                                      \
            const int ni = (NH) * 2 + nl;                                     \
            acc[(MH)*4 + mi][ni] = __builtin_amdgcn_mfma_f32_16x16x32_bf16(   \
                af[mi][0], bfr[ni][0], acc[(MH)*4 + mi][ni], 0, 0, 0);        \
            acc[(MH)*4 + mi][ni] = __builtin_amdgcn_mfma_f32_16x16x32_bf16(   \
                af[mi][1], bfr[ni][1], acc[(MH)*4 + mi][ni], 0, 0, 0);        \
        }                                                                     \
    __builtin_amdgcn_s_setprio(0);

#define FENCE asm volatile("" ::: "memory")
#define BAR   __builtin_amdgcn_s_barrier(); FENCE
#define LGKM0 asm volatile("s_waitcnt lgkmcnt(0)" ::: "memory");              \
              __builtin_amdgcn_sched_barrier(0)

    // ITER(tile T in CUR): issue tile T+1 into NXT (8 loads); vmcnt(8) ->
    // tile T (issued one full tile ago) has landed; barrier; 4 phases:
    //   P0: ds af(mh0)+bfr(nh0) [12] | MFMA Q00
    //   P1: ds bfr(nh1)          [4] | MFMA Q01
    //   P2: ds af(mh1)           [8] | MFMA Q11
    //   P3: (regs held)              | MFMA Q10
    // Nothing reads CUR after P2's closing barrier, so the next ITER's
    // stages (into CUR) are safe.
#define ITER(CUR, NXT, DOISS, VMS)                                            \
    {                                                                         \
        if (DOISS) {                                                          \
            _Pragma("unroll")                                                 \
            for (int i = 0; i < 8; ++i)                                       \
                GLOAD_LDS16(gSrc[i] + koff, (NXT) + dOff[i]);                 \
            koff += 64;                                                       \
        }                                                                     \
        asm volatile("s_waitcnt vmcnt(" VMS ")" ::: "memory");                \
        BAR;                                                                  \
        DS_AF(CUR, 0); DS_BF(CUR, 0);                                         \
        asm volatile("s_waitcnt lgkmcnt(8)" ::: "memory");                    \
        BAR;                                                                  \
        LGKM0; MQ(0, 0);                                                      \
        BAR;                                                                  \
        DS_BF(CUR, 1);                                                        \
        BAR;                                                                  \
        LGKM0; MQ(0, 1);                                                      \
        BAR;                                                                  \
        DS_AF(CUR, 1);                                                        \
        BAR;                                                                  \
        LGKM0; MQ(1, 1);                                                      \
        BAR;                                                                  \
        MQ(1, 0);                                                             \
    }

    // prologue: issue tile 0 into buf0
#pragma unroll
    for (int i = 0; i < 8; ++i) GLOAD_LDS16(gSrc[i], b0 + dOff[i]);

    int koff = 64;   // k element-offset of the next tile to issue (tile 1)

#pragma unroll 1
    for (int t2 = 0; t2 < (NT - 2) / 2; ++t2) {
        ITER(b0, b1, 1, "8");
        ITER(b1, b0, 1, "8");
    }
    ITER(b0, b1, 1, "8");   // tile 62, issues tile 63
    ITER(b1, b0, 0, "0");   // tile 63, drain

#undef ITER
#undef MQ
#undef DS_BF
#undef DS_AF

    // epilogue: bias add + store (C/D layout: col=lane&15, row=(lane>>4)*4+j)
#pragma unroll
    for (int ni = 0; ni < 4; ++ni) {
        const int col = bn + wc * 64 + ni * 16 + (lane & 15);
        const float bv = bias[col];
#pragma unroll
        for (int mi = 0; mi < 8; ++mi) {
            const int rbase = bm + wr * 128 + mi * 16 + (lane >> 4) * 4;
#pragma unroll
            for (int j = 0; j < 4; ++j)
                C[(size_t)(rbase + j) * Ndim + col] = acc[mi][ni][j] + bv;
        }
    }
}

// ---------------------------------------------------------------------------
// Fallback (only if ws too small): slow but correct fp32 row-per-block kernel
// ---------------------------------------------------------------------------
__global__ __launch_bounds__(256) void naive_row_kernel(
    const float* __restrict__ x, const float* __restrict__ W,
    const float* __restrict__ bias, const float* __restrict__ A,
    const float* __restrict__ Bm, float* __restrict__ out)
{
    __shared__ float sx[Kdim];
    __shared__ float st[ER];
    const int m = blockIdx.x;
    const float* xr = x + (size_t)m * Kdim;
    for (int i = threadIdx.x; i < Kdim; i += 256) sx[i] = xr[i];
    __syncthreads();
    if (threadIdx.x < ER) {
        const float* ar = A + (size_t)threadIdx.x * Kdim;
        float s = 0.f;
        for (int i = 0; i < Kdim; ++i) s += sx[i] * ar[i];
        st[threadIdx.x] = s;
    }
    __syncthreads();
    for (int o = threadIdx.x; o < Ndim; o += 256) {
        const float* wr = W + (size_t)o * Kdim;
        float s = bias[o];
        for (int i = 0; i < Kdim; ++i) s += sx[i] * wr[i];
        float l = 0.f;
        for (int e = 0; e < 8; ++e) {
            const float* bp = Bm + ((size_t)e * Ndim + o) * 8;
            for (int r = 0; r < 8; ++r) l += st[e * 8 + r] * bp[r];
        }
        out[(size_t)m * Ndim + o] = s + LSCALE * l;
    }
}

extern "C" void kernel_launch(void* const* d_in, const int* in_sizes, int n_in,
                              void* d_out, int out_size, void* d_ws, size_t ws_size,
                              hipStream_t stream)
{
    const float* x  = (const float*)d_in[0];
    const float* W  = (const float*)d_in[1];
    const float* b  = (const float*)d_in[2];
    const float* A  = (const float*)d_in[3];
    const float* Bm = (const float*)d_in[4];
    float* out = (float*)d_out;

    const size_t xb_bytes = (size_t)Mdim * Kdim * 2;   // 64 MB
    const size_t wb_bytes = (size_t)Ndim * Kdim * 2;   // 32 MB

    if (ws_size >= xb_bytes + wb_bytes) {
        u16* Xb = (u16*)d_ws;
        u16* Wb = (u16*)((char*)d_ws + xb_bytes);
        cvt_x_kernel<<<(Mdim * (size_t)Kdim) / 8 / 256, 256, 0, stream>>>(x, Xb);
        weff_kernel<<<dim3(Kdim / 128, Ndim / 64), 256, 0, stream>>>(W, A, Bm, Wb);
        gemm_bias_kernel<<<dim3((Mdim / BM) * (Ndim / BN)), 512, 0, stream>>>(Xb, Wb, b, out);
    } else {
        naive_row_kernel<<<Mdim, 256, 0, stream>>>(x, W, b, A, Bm, out);
    }
}

// Round 5
// 293.101 us; speedup vs baseline: 1.5164x; 1.0648x over previous
//
#include <hip/hip_runtime.h>
#include <hip/hip_bf16.h>

typedef unsigned short u16;
typedef __bf16 bf16x8 __attribute__((ext_vector_type(8)));
typedef float f32x4 __attribute__((ext_vector_type(4)));

// Problem constants (B=4, S=2048, D=4096, E=8, r=8)
constexpr int Mdim = 8192;   // B*S
constexpr int Ndim = 4096;   // D (output features)
constexpr int Kdim = 4096;   // D (input features)
constexpr int ER   = 64;     // E*r
constexpr float LSCALE = 2.0f;  // alpha/r = 16/8

// round-to-nearest-even fp32 -> bf16 (finite inputs)
__device__ __forceinline__ u16 f2bf(float f) {
    union { float f; unsigned u; } v; v.f = f;
    unsigned r = v.u + 0x7fffu + ((v.u >> 16) & 1u);
    return (u16)(r >> 16);
}

#define GLOAD_LDS16(g, l)                                             \
    __builtin_amdgcn_global_load_lds(                                 \
        (const __attribute__((address_space(1))) void*)(g),           \
        (__attribute__((address_space(3))) void*)(l), 16, 0, 0)

// ---------------------------------------------------------------------------
// Kernel 1: W_eff[o,i] = W[o,i] + SCALE * sum_{er} Bcat[o,er]*Acat[er,i] (bf16)
// ---------------------------------------------------------------------------
__global__ __launch_bounds__(256) void weff_kernel(
    const float* __restrict__ W, const float* __restrict__ A,
    const float* __restrict__ Bm, u16* __restrict__ Wb)
{
    __shared__ __align__(16) float sAc[ER][128];
    __shared__ __align__(16) float sBc[64][ER];

    const int t  = threadIdx.x;
    const int i0 = blockIdx.x * 128;
    const int o0 = blockIdx.y * 64;

#pragma unroll
    for (int p = 0; p < 8; ++p) {
        int lin = p * 1024 + t * 4;
        int er = lin >> 7, ci = lin & 127;
        *(float4*)&sAc[er][ci] = *(const float4*)(A + (size_t)er * Kdim + i0 + ci);
    }
    {
        int ol = t >> 2;
        int c  = (t & 3) * 16;
#pragma unroll
        for (int q = 0; q < 2; ++q) {
            int er = c + q * 8;
            int e  = er >> 3;
            const float* src = Bm + ((size_t)e * Ndim + (o0 + ol)) * 8;
            *(float4*)&sBc[ol][er]     = *(const float4*)(src);
            *(float4*)&sBc[ol][er + 4] = *(const float4*)(src + 4);
        }
    }
    __syncthreads();

    const int tx = t & 31;
    const int ty = t >> 5;
    float acc[8][4] = {};
#pragma unroll 4
    for (int er = 0; er < ER; ++er) {
        float4 a = *(const float4*)&sAc[er][tx * 4];
#pragma unroll
        for (int q = 0; q < 8; ++q) {
            float bv = sBc[q * 8 + ty][er];
            acc[q][0] += bv * a.x;
            acc[q][1] += bv * a.y;
            acc[q][2] += bv * a.z;
            acc[q][3] += bv * a.w;
        }
    }
#pragma unroll
    for (int q = 0; q < 8; ++q) {
        int o = o0 + q * 8 + ty;
        const float4 w = *(const float4*)(W + (size_t)o * Kdim + i0 + tx * 4);
        ushort4 st;
        st.x = f2bf(w.x + LSCALE * acc[q][0]);
        st.y = f2bf(w.y + LSCALE * acc[q][1]);
        st.z = f2bf(w.z + LSCALE * acc[q][2]);
        st.w = f2bf(w.w + LSCALE * acc[q][3]);
        *(ushort4*)(Wb + (size_t)o * Kdim + i0 + tx * 4) = st;
    }
}

// ---------------------------------------------------------------------------
// Kernel 2: x fp32 -> bf16, 8 elements/thread
// ---------------------------------------------------------------------------
__global__ __launch_bounds__(256) void cvt_x_kernel(
    const float* __restrict__ x, u16* __restrict__ xb)
{
    size_t i = (size_t)blockIdx.x * blockDim.x + threadIdx.x;
    const float4 v0 = *(const float4*)(x + i * 8);
    const float4 v1 = *(const float4*)(x + i * 8 + 4);
    uint4 o;
    o.x = (unsigned)f2bf(v0.x) | ((unsigned)f2bf(v0.y) << 16);
    o.y = (unsigned)f2bf(v0.z) | ((unsigned)f2bf(v0.w) << 16);
    o.z = (unsigned)f2bf(v1.x) | ((unsigned)f2bf(v1.y) << 16);
    o.w = (unsigned)f2bf(v1.z) | ((unsigned)f2bf(v1.w) << 16);
    *(uint4*)(xb + i * 8) = o;
}

// ---------------------------------------------------------------------------
// Kernel 3: 256x256x64 GEMM. 3-barrier software-pipelined K-loop:
//  - held-back quadrant: Q10 of tile T issues in tile T+1's first interval,
//    overlapping the first ds batch (register lifetimes resolved purely by
//    program order -- no extra fragment arrays).
//  - gloads for T+1 issue AFTER the tile-top barrier (provably race-free
//    vs other waves' reads of the buffer being overwritten).
//  - vmcnt(0) at tile top == "tile T landed" since T+1 not yet issued.
// 512 threads = 8 waves (2 M x 4 N); per-wave 128x64 out = acc[8][4] f32x4.
// LDS 128 KiB: per buf {A[256][64], B[256][64]} bf16, double-buffered.
// Full XOR swizzle (chunk ^= row&7) on both sides; bank conflicts = 0.
// ---------------------------------------------------------------------------
constexpr int BM = 256, BN = 256, BK = 64;
constexpr int NT = Kdim / BK;  // 64

__global__ __launch_bounds__(512, 2) void gemm_bias_kernel(
    const u16* __restrict__ Xb, const u16* __restrict__ Wb,
    const float* __restrict__ bias, float* __restrict__ C)
{
    __shared__ __align__(16) u16 lds[65536];   // 128 KiB

    const int t    = threadIdx.x;
    const int lane = t & 63;
    const int wv   = t >> 6;
    const int wr   = wv >> 2;   // 0..1
    const int wc   = wv & 3;    // 0..3

    // XCD-aware swizzle: 512 blocks = 8 XCDs x 64; each XCD owns a 16x4 region
    const int wg  = blockIdx.x;
    const int xcd = wg & 7, lid = wg >> 3;
    const int mt  = (xcd & 1) * 16 + (lid >> 2);   // 0..31
    const int ntl = (xcd >> 1) * 4 + (lid & 3);    // 0..15
    const int bm  = mt * BM;
    const int bn  = ntl * BN;

    u16* b0 = lds;            // buf0: A at [0,16384), B at [16384,32768)
    u16* b1 = lds + 32768;    // buf1

    // --- staging: 8 x global_load_lds(16B) per thread per K-tile ---
    const u16* gSrc[8]; int dOff[8];
#pragma unroll
    for (int i = 0; i < 8; ++i) {
        const int sub = i & 3;
        const int isB = i >> 2;
        const int c   = sub * 512 + t;                    // 0..2047
        const int row = c >> 3;                           // 0..255
        const int scl = ((c ^ row) & 7) * 8;              // swizzled col (u16)
        gSrc[i] = (isB ? Wb + (size_t)(bn + row) * Kdim
                       : Xb + (size_t)(bm + row) * Kdim) + scl;
        dOff[i] = isB * 16384 + c * 8;
    }

    // --- fragment ds_read addressing (swizzled) ---
    const int fr  = lane & 15;                               // row-in-16
    const int cp0 = (((lane >> 4)    ) ^ (lane & 7)) * 8;    // kk=0 chunk col
    const int cp1 = (((lane >> 4) + 4) ^ (lane & 7)) * 8;    // kk=1 chunk col

    f32x4 acc[8][4];
#pragma unroll
    for (int i = 0; i < 8; ++i)
#pragma unroll
        for (int j = 0; j < 4; ++j)
            acc[i][j] = f32x4{0.f, 0.f, 0.f, 0.f};

    bf16x8 af[4][2];    // A fragments for the current m-half (mh0 or mh1)
    bf16x8 bfr[4][2];   // all four B n-fragments

#define DS_AF(BUF, MH)                                                        \
    _Pragma("unroll")                                                         \
    for (int mi = 0; mi < 4; ++mi) {                                          \
        const int rb = (wr * 128 + (MH) * 64 + mi * 16 + fr) * 64;            \
        af[mi][0] = *(const bf16x8*)&(BUF)[rb + cp0];                         \
        af[mi][1] = *(const bf16x8*)&(BUF)[rb + cp1];                         \
    }

#define DS_BF(BUF, NH)                                                        \
    _Pragma("unroll")                                                         \
    for (int nl = 0; nl < 2; ++nl) {                                          \
        const int ni = (NH) * 2 + nl;                                         \
        const int rb = 16384 + (wc * 64 + ni * 16 + fr) * 64;                 \
        bfr[ni][0] = *(const bf16x8*)&(BUF)[rb + cp0];                        \
        bfr[ni][1] = *(const bf16x8*)&(BUF)[rb + cp1];                        \
    }

#define MQ(MH, NH)                                                            \
    __builtin_amdgcn_s_setprio(1);                                            \
    _Pragma("unroll")                                                         \
    for (int mi = 0; mi < 4; ++mi)                                            \
        _Pragma("unroll")                                                     \
        for (int nl = 0; nl < 2; ++nl) {                                      \
            const int ni = (NH) * 2 + nl;                                     \
            acc[(MH)*4 + mi][ni] = __builtin_amdgcn_mfma_f32_16x16x32_bf16(   \
                af[mi][0], bfr[ni][0], acc[(MH)*4 + mi][ni], 0, 0, 0);        \
            acc[(MH)*4 + mi][ni] = __builtin_amdgcn_mfma_f32_16x16x32_bf16(   \
                af[mi][1], bfr[ni][1], acc[(MH)*4 + mi][ni], 0, 0, 0);        \
        }                                                                     \
    __builtin_amdgcn_s_setprio(0);

#define FENCE asm volatile("" ::: "memory")
#define BAR   __builtin_amdgcn_s_barrier(); FENCE
#define LGKM0 asm volatile("s_waitcnt lgkmcnt(0)" ::: "memory");              \
              __builtin_amdgcn_sched_barrier(0)

    // TILE(T): 3 barriers, held-back Q10.
    //  vmcnt(0): tile T's 8 gloads (issued in T-1) landed; T+1's not issued.
    //  Interval a: MQ10_held(T-1) + gloads(T+1) + DS{afA,bfr01}; LGKM0; MQ00
    //  Interval b: DS{bfr23}; LGKM0; MQ01; DS{afB}
    //  Interval c: LGKM0; MQ11      (Q10 of T held to tile T+1)
    // WAR safety (single af/bfr arrays): MQ10_held reads af(=afB of T-1) and
    // bfr01(T-1) BEFORE DS_AF(0)/DS_BF(0) overwrite them; MQ01 reads af(=afA)
    // BEFORE DS_AF(1) overwrites. All by program order.
#define TILE(CUR, NXT, FIRST, LAST)                                           \
    {                                                                         \
        asm volatile("s_waitcnt vmcnt(0)" ::: "memory");                      \
        BAR;                                                                  \
        if (!(FIRST)) { MQ(1, 0); }                                           \
        if (!(LAST)) {                                                        \
            _Pragma("unroll")                                                 \
            for (int i = 0; i < 8; ++i)                                       \
                GLOAD_LDS16(gSrc[i] + koff, (NXT) + dOff[i]);                 \
            koff += 64;                                                       \
        }                                                                     \
        DS_AF(CUR, 0);                                                        \
        DS_BF(CUR, 0);                                                        \
        LGKM0;                                                                \
        MQ(0, 0);                                                             \
        BAR;                                                                  \
        DS_BF(CUR, 1);                                                        \
        LGKM0;                                                                \
        MQ(0, 1);                                                             \
        DS_AF(CUR, 1);                                                        \
        BAR;                                                                  \
        LGKM0;                                                                \
        MQ(1, 1);                                                             \
    }

    // prologue: issue tile 0 into buf0
#pragma unroll
    for (int i = 0; i < 8; ++i) GLOAD_LDS16(gSrc[i], b0 + dOff[i]);

    int koff = 64;   // k element-offset of the next tile to issue (tile 1)

    TILE(b0, b1, 1, 0);                 // T0
#pragma unroll 1
    for (int t2 = 0; t2 < (NT - 2) / 2; ++t2) {   // T1..T62 (31 pairs)
        TILE(b1, b0, 0, 0);
        TILE(b0, b1, 0, 0);
    }
    TILE(b1, b0, 0, 1);                 // T63 (no prefetch)
    MQ(1, 0);                           // drain held Q10 of T63

#undef TILE
#undef MQ
#undef DS_BF
#undef DS_AF

    // epilogue: bias add + store (C/D layout: col=lane&15, row=(lane>>4)*4+j)
#pragma unroll
    for (int ni = 0; ni < 4; ++ni) {
        const int col = bn + wc * 64 + ni * 16 + (lane & 15);
        const float bv = bias[col];
#pragma unroll
        for (int mi = 0; mi < 8; ++mi) {
            const int rbase = bm + wr * 128 + mi * 16 + (lane >> 4) * 4;
#pragma unroll
            for (int j = 0; j < 4; ++j)
                C[(size_t)(rbase + j) * Ndim + col] = acc[mi][ni][j] + bv;
        }
    }
}

// ---------------------------------------------------------------------------
// Fallback (only if ws too small): slow but correct fp32 row-per-block kernel
// ---------------------------------------------------------------------------
__global__ __launch_bounds__(256) void naive_row_kernel(
    const float* __restrict__ x, const float* __restrict__ W,
    const float* __restrict__ bias, const float* __restrict__ A,
    const float* __restrict__ Bm, float* __restrict__ out)
{
    __shared__ float sx[Kdim];
    __shared__ float st[ER];
    const int m = blockIdx.x;
    const float* xr = x + (size_t)m * Kdim;
    for (int i = threadIdx.x; i < Kdim; i += 256) sx[i] = xr[i];
    __syncthreads();
    if (threadIdx.x < ER) {
        const float* ar = A + (size_t)threadIdx.x * Kdim;
        float s = 0.f;
        for (int i = 0; i < Kdim; ++i) s += sx[i] * ar[i];
        st[threadIdx.x] = s;
    }
    __syncthreads();
    for (int o = threadIdx.x; o < Ndim; o += 256) {
        const float* wr = W + (size_t)o * Kdim;
        float s = bias[o];
        for (int i = 0; i < Kdim; ++i) s += sx[i] * wr[i];
        float l = 0.f;
        for (int e = 0; e < 8; ++e) {
            const float* bp = Bm + ((size_t)e * Ndim + o) * 8;
            for (int r = 0; r < 8; ++r) l += st[e * 8 + r] * bp[r];
        }
        out[(size_t)m * Ndim + o] = s + LSCALE * l;
    }
}

extern "C" void kernel_launch(void* const* d_in, const int* in_sizes, int n_in,
                              void* d_out, int out_size, void* d_ws, size_t ws_size,
                              hipStream_t stream)
{
    const float* x  = (const float*)d_in[0];
    const float* W  = (const float*)d_in[1];
    const float* b  = (const float*)d_in[2];
    const float* A  = (const float*)d_in[3];
    const float* Bm = (const float*)d_in[4];
    float* out = (float*)d_out;

    const size_t xb_bytes = (size_t)Mdim * Kdim * 2;   // 64 MB
    const size_t wb_bytes = (size_t)Ndim * Kdim * 2;   // 32 MB

    if (ws_size >= xb_bytes + wb_bytes) {
        u16* Xb = (u16*)d_ws;
        u16* Wb = (u16*)((char*)d_ws + xb_bytes);
        cvt_x_kernel<<<(Mdim * (size_t)Kdim) / 8 / 256, 256, 0, stream>>>(x, Xb);
        weff_kernel<<<dim3(Kdim / 128, Ndim / 64), 256, 0, stream>>>(W, A, Bm, Wb);
        gemm_bias_kernel<<<dim3((Mdim / BM) * (Ndim / BN)), 512, 0, stream>>>(Xb, Wb, b, out);
    } else {
        naive_row_kernel<<<Mdim, 256, 0, stream>>>(x, W, b, A, Bm, out);
    }
}

// Round 6
// 284.734 us; speedup vs baseline: 1.5610x; 1.0294x over previous
//
#include <hip/hip_runtime.h>
#include <hip/hip_bf16.h>

typedef unsigned short u16;
typedef __bf16 bf16x8 __attribute__((ext_vector_type(8)));
typedef float f32x4 __attribute__((ext_vector_type(4)));

// Problem constants (B=4, S=2048, D=4096, E=8, r=8)
constexpr int Mdim = 8192;   // B*S
constexpr int Ndim = 4096;   // D (output features)
constexpr int Kdim = 4096;   // D (input features)
constexpr int ER   = 64;     // E*r
constexpr float LSCALE = 2.0f;  // alpha/r = 16/8

// round-to-nearest-even fp32 -> bf16 (finite inputs)
__device__ __forceinline__ u16 f2bf(float f) {
    union { float f; unsigned u; } v; v.f = f;
    unsigned r = v.u + 0x7fffu + ((v.u >> 16) & 1u);
    return (u16)(r >> 16);
}

#define GLOAD_LDS16(g, l)                                             \
    __builtin_amdgcn_global_load_lds(                                 \
        (const __attribute__((address_space(1))) void*)(g),           \
        (__attribute__((address_space(3))) void*)(l), 16, 0, 0)

// ---------------------------------------------------------------------------
// Kernel 1: W_eff[o,i] = W[o,i] + SCALE * sum_{er} Bcat[o,er]*Acat[er,i] (bf16)
// ---------------------------------------------------------------------------
__global__ __launch_bounds__(256) void weff_kernel(
    const float* __restrict__ W, const float* __restrict__ A,
    const float* __restrict__ Bm, u16* __restrict__ Wb)
{
    __shared__ __align__(16) float sAc[ER][128];
    __shared__ __align__(16) float sBc[64][ER];

    const int t  = threadIdx.x;
    const int i0 = blockIdx.x * 128;
    const int o0 = blockIdx.y * 64;

#pragma unroll
    for (int p = 0; p < 8; ++p) {
        int lin = p * 1024 + t * 4;
        int er = lin >> 7, ci = lin & 127;
        *(float4*)&sAc[er][ci] = *(const float4*)(A + (size_t)er * Kdim + i0 + ci);
    }
    {
        int ol = t >> 2;
        int c  = (t & 3) * 16;
#pragma unroll
        for (int q = 0; q < 2; ++q) {
            int er = c + q * 8;
            int e  = er >> 3;
            const float* src = Bm + ((size_t)e * Ndim + (o0 + ol)) * 8;
            *(float4*)&sBc[ol][er]     = *(const float4*)(src);
            *(float4*)&sBc[ol][er + 4] = *(const float4*)(src + 4);
        }
    }
    __syncthreads();

    const int tx = t & 31;
    const int ty = t >> 5;
    float acc[8][4] = {};
#pragma unroll 4
    for (int er = 0; er < ER; ++er) {
        float4 a = *(const float4*)&sAc[er][tx * 4];
#pragma unroll
        for (int q = 0; q < 8; ++q) {
            float bv = sBc[q * 8 + ty][er];
            acc[q][0] += bv * a.x;
            acc[q][1] += bv * a.y;
            acc[q][2] += bv * a.z;
            acc[q][3] += bv * a.w;
        }
    }
#pragma unroll
    for (int q = 0; q < 8; ++q) {
        int o = o0 + q * 8 + ty;
        const float4 w = *(const float4*)(W + (size_t)o * Kdim + i0 + tx * 4);
        ushort4 st;
        st.x = f2bf(w.x + LSCALE * acc[q][0]);
        st.y = f2bf(w.y + LSCALE * acc[q][1]);
        st.z = f2bf(w.z + LSCALE * acc[q][2]);
        st.w = f2bf(w.w + LSCALE * acc[q][3]);
        *(ushort4*)(Wb + (size_t)o * Kdim + i0 + tx * 4) = st;
    }
}

// ---------------------------------------------------------------------------
// Kernel 2: x fp32 -> bf16, 8 elements/thread
// ---------------------------------------------------------------------------
__global__ __launch_bounds__(256) void cvt_x_kernel(
    const float* __restrict__ x, u16* __restrict__ xb)
{
    size_t i = (size_t)blockIdx.x * blockDim.x + threadIdx.x;
    const float4 v0 = *(const float4*)(x + i * 8);
    const float4 v1 = *(const float4*)(x + i * 8 + 4);
    uint4 o;
    o.x = (unsigned)f2bf(v0.x) | ((unsigned)f2bf(v0.y) << 16);
    o.y = (unsigned)f2bf(v0.z) | ((unsigned)f2bf(v0.w) << 16);
    o.z = (unsigned)f2bf(v1.x) | ((unsigned)f2bf(v1.y) << 16);
    o.w = (unsigned)f2bf(v1.z) | ((unsigned)f2bf(v1.w) << 16);
    *(uint4*)(xb + i * 8) = o;
}

// ---------------------------------------------------------------------------
// Kernel 3: 256x256x64 GEMM. ONE barrier per K-tile; waves drift within the
// tile so MFMA (2483 cyc/CU/tile) and LDS reads (2304 cyc/CU/tile) overlap
// across waves instead of serializing (round-5 lockstep measured ~4700 =
// 2483+2304 serial). Correctness: within a tile no wave writes CUR (gloads
// target NXT); every wave's ds_reads are consumed (lgkm-drained by compiler
// waits before its MFMAs) before it reaches the next tile-top barrier, so
// the tile-top vmcnt(0)+lgkmcnt(0)+barrier is the only sync needed.
// Held-back quadrant Q10 of tile T runs at tile T+1's top (register-only,
// fills the MFMA pipe during the post-barrier DS burst; WAR on shared
// af/bfr arrays resolved by per-wave program order).
// 512 threads = 8 waves (2 M x 4 N); per-wave 128x64 out = acc[8][4] f32x4.
// LDS 128 KiB: per buf {A[256][64], B[256][64]} bf16, double-buffered.
// Full XOR swizzle (chunk ^= row&7) on both sides; bank conflicts = 0.
// ---------------------------------------------------------------------------
constexpr int BM = 256, BN = 256, BK = 64;
constexpr int NT = Kdim / BK;  // 64

__global__ __launch_bounds__(512, 2) void gemm_bias_kernel(
    const u16* __restrict__ Xb, const u16* __restrict__ Wb,
    const float* __restrict__ bias, float* __restrict__ C)
{
    __shared__ __align__(16) u16 lds[65536];   // 128 KiB

    const int t    = threadIdx.x;
    const int lane = t & 63;
    const int wv   = t >> 6;
    const int wr   = wv >> 2;   // 0..1
    const int wc   = wv & 3;    // 0..3

    // XCD-aware swizzle: 512 blocks = 8 XCDs x 64; each XCD owns a 16x4 region
    const int wg  = blockIdx.x;
    const int xcd = wg & 7, lid = wg >> 3;
    const int mt  = (xcd & 1) * 16 + (lid >> 2);   // 0..31
    const int ntl = (xcd >> 1) * 4 + (lid & 3);    // 0..15
    const int bm  = mt * BM;
    const int bn  = ntl * BN;

    u16* b0 = lds;            // buf0: A at [0,16384), B at [16384,32768)
    u16* b1 = lds + 32768;    // buf1

    // --- staging: 8 x global_load_lds(16B) per thread per K-tile ---
    const u16* gSrc[8]; int dOff[8];
#pragma unroll
    for (int i = 0; i < 8; ++i) {
        const int sub = i & 3;
        const int isB = i >> 2;
        const int c   = sub * 512 + t;                    // 0..2047
        const int row = c >> 3;                           // 0..255
        const int scl = ((c ^ row) & 7) * 8;              // swizzled col (u16)
        gSrc[i] = (isB ? Wb + (size_t)(bn + row) * Kdim
                       : Xb + (size_t)(bm + row) * Kdim) + scl;
        dOff[i] = isB * 16384 + c * 8;
    }

    // --- fragment ds_read addressing (swizzled) ---
    const int fr  = lane & 15;                               // row-in-16
    const int cp0 = (((lane >> 4)    ) ^ (lane & 7)) * 8;    // kk=0 chunk col
    const int cp1 = (((lane >> 4) + 4) ^ (lane & 7)) * 8;    // kk=1 chunk col

    f32x4 acc[8][4];
#pragma unroll
    for (int i = 0; i < 8; ++i)
#pragma unroll
        for (int j = 0; j < 4; ++j)
            acc[i][j] = f32x4{0.f, 0.f, 0.f, 0.f};

    bf16x8 af[4][2];    // A fragments for the current m-half (mh0 or mh1)
    bf16x8 bfr[4][2];   // all four B n-fragments

#define DS_AF(BUF, MH)                                                        \
    _Pragma("unroll")                                                         \
    for (int mi = 0; mi < 4; ++mi) {                                          \
        const int rb = (wr * 128 + (MH) * 64 + mi * 16 + fr) * 64;            \
        af[mi][0] = *(const bf16x8*)&(BUF)[rb + cp0];                         \
        af[mi][1] = *(const bf16x8*)&(BUF)[rb + cp1];                         \
    }

#define DS_BF(BUF, NH)                                                        \
    _Pragma("unroll")                                                         \
    for (int nl = 0; nl < 2; ++nl) {                                          \
        const int ni = (NH) * 2 + nl;                                         \
        const int rb = 16384 + (wc * 64 + ni * 16 + fr) * 64;                 \
        bfr[ni][0] = *(const bf16x8*)&(BUF)[rb + cp0];                        \
        bfr[ni][1] = *(const bf16x8*)&(BUF)[rb + cp1];                        \
    }

#define MQ(MH, NH)                                                            \
    __builtin_amdgcn_s_setprio(1);                                            \
    _Pragma("unroll")                                                         \
    for (int mi = 0; mi < 4; ++mi)                                            \
        _Pragma("unroll")                                                     \
        for (int nl = 0; nl < 2; ++nl) {                                      \
            const int ni = (NH) * 2 + nl;                                     \
            acc[(MH)*4 + mi][ni] = __builtin_amdgcn_mfma_f32_16x16x32_bf16(   \
                af[mi][0], bfr[ni][0], acc[(MH)*4 + mi][ni], 0, 0, 0);        \
            acc[(MH)*4 + mi][ni] = __builtin_amdgcn_mfma_f32_16x16x32_bf16(   \
                af[mi][1], bfr[ni][1], acc[(MH)*4 + mi][ni], 0, 0, 0);        \
        }                                                                     \
    __builtin_amdgcn_s_setprio(0);

#define FENCE asm volatile("" ::: "memory")
#define BAR   __builtin_amdgcn_s_barrier(); FENCE

    // TILE(T): ONE barrier. vmcnt(0): tile T's gloads (issued in T-1) landed
    // (T+1's not yet issued); lgkmcnt(0) is already-drained belt-and-braces.
    // Then per-wave straight-line: held MQ10(T-1) [register-only, must
    // precede DS_AF0/DS_BF0 which overwrite its operands], gloads(T+1) into
    // NXT, 24 ds_reads of CUR interleaved with the 4 MFMA quadrants; the
    // compiler emits counted lgkmcnt before each dependent MFMA cluster.
    // No mid-tile barriers: waves drift; MFMA of one wave overlaps DS of
    // another (m114), setprio favors the MFMA-cluster waves.
#define TILE(CUR, NXT, FIRST, LAST)                                           \
    {                                                                         \
        asm volatile("s_waitcnt vmcnt(0) lgkmcnt(0)" ::: "memory");           \
        BAR;                                                                  \
        if (!(FIRST)) { MQ(1, 0); }                                           \
        if (!(LAST)) {                                                        \
            _Pragma("unroll")                                                 \
            for (int i = 0; i < 8; ++i)                                       \
                GLOAD_LDS16(gSrc[i] + koff, (NXT) + dOff[i]);                 \
            koff += 64;                                                       \
        }                                                                     \
        DS_AF(CUR, 0);                                                        \
        DS_BF(CUR, 0);                                                        \
        MQ(0, 0);                                                             \
        DS_BF(CUR, 1);                                                        \
        MQ(0, 1);                                                             \
        DS_AF(CUR, 1);                                                        \
        MQ(1, 1);                                                             \
    }

    // prologue: issue tile 0 into buf0
#pragma unroll
    for (int i = 0; i < 8; ++i) GLOAD_LDS16(gSrc[i], b0 + dOff[i]);

    int koff = 64;   // k element-offset of the next tile to issue (tile 1)

    TILE(b0, b1, 1, 0);                 // T0
#pragma unroll 1
    for (int t2 = 0; t2 < (NT - 2) / 2; ++t2) {   // T1..T62 (31 pairs)
        TILE(b1, b0, 0, 0);
        TILE(b0, b1, 0, 0);
    }
    TILE(b1, b0, 0, 1);                 // T63 (no prefetch)
    MQ(1, 0);                           // drain held Q10 of T63

#undef TILE
#undef MQ
#undef DS_BF
#undef DS_AF

    // epilogue: bias add + store (C/D layout: col=lane&15, row=(lane>>4)*4+j)
#pragma unroll
    for (int ni = 0; ni < 4; ++ni) {
        const int col = bn + wc * 64 + ni * 16 + (lane & 15);
        const float bv = bias[col];
#pragma unroll
        for (int mi = 0; mi < 8; ++mi) {
            const int rbase = bm + wr * 128 + mi * 16 + (lane >> 4) * 4;
#pragma unroll
            for (int j = 0; j < 4; ++j)
                C[(size_t)(rbase + j) * Ndim + col] = acc[mi][ni][j] + bv;
        }
    }
}

// ---------------------------------------------------------------------------
// Fallback (only if ws too small): slow but correct fp32 row-per-block kernel
// ---------------------------------------------------------------------------
__global__ __launch_bounds__(256) void naive_row_kernel(
    const float* __restrict__ x, const float* __restrict__ W,
    const float* __restrict__ bias, const float* __restrict__ A,
    const float* __restrict__ Bm, float* __restrict__ out)
{
    __shared__ float sx[Kdim];
    __shared__ float st[ER];
    const int m = blockIdx.x;
    const float* xr = x + (size_t)m * Kdim;
    for (int i = threadIdx.x; i < Kdim; i += 256) sx[i] = xr[i];
    __syncthreads();
    if (threadIdx.x < ER) {
        const float* ar = A + (size_t)threadIdx.x * Kdim;
        float s = 0.f;
        for (int i = 0; i < Kdim; ++i) s += sx[i] * ar[i];
        st[threadIdx.x] = s;
    }
    __syncthreads();
    for (int o = threadIdx.x; o < Ndim; o += 256) {
        const float* wr = W + (size_t)o * Kdim;
        float s = bias[o];
        for (int i = 0; i < Kdim; ++i) s += sx[i] * wr[i];
        float l = 0.f;
        for (int e = 0; e < 8; ++e) {
            const float* bp = Bm + ((size_t)e * Ndim + o) * 8;
            for (int r = 0; r < 8; ++r) l += st[e * 8 + r] * bp[r];
        }
        out[(size_t)m * Ndim + o] = s + LSCALE * l;
    }
}

extern "C" void kernel_launch(void* const* d_in, const int* in_sizes, int n_in,
                              void* d_out, int out_size, void* d_ws, size_t ws_size,
                              hipStream_t stream)
{
    const float* x  = (const float*)d_in[0];
    const float* W  = (const float*)d_in[1];
    const float* b  = (const float*)d_in[2];
    const float* A  = (const float*)d_in[3];
    const float* Bm = (const float*)d_in[4];
    float* out = (float*)d_out;

    const size_t xb_bytes = (size_t)Mdim * Kdim * 2;   // 64 MB
    const size_t wb_bytes = (size_t)Ndim * Kdim * 2;   // 32 MB

    if (ws_size >= xb_bytes + wb_bytes) {
        u16* Xb = (u16*)d_ws;
        u16* Wb = (u16*)((char*)d_ws + xb_bytes);
        cvt_x_kernel<<<(Mdim * (size_t)Kdim) / 8 / 256, 256, 0, stream>>>(x, Xb);
        weff_kernel<<<dim3(Kdim / 128, Ndim / 64), 256, 0, stream>>>(W, A, Bm, Wb);
        gemm_bias_kernel<<<dim3((Mdim / BM) * (Ndim / BN)), 512, 0, stream>>>(Xb, Wb, b, out);
    } else {
        naive_row_kernel<<<Mdim, 256, 0, stream>>>(x, W, b, A, Bm, out);
    }
}